// Round 3
// baseline (475.351 us; speedup 1.0000x reference)
//
#include <hip/hip_runtime.h>

// 1-D multi-resolution linear interp, 6 levels (sizes 8..256, 8 channels),
// N=2M points -> (N, 48) f32.  Write-bound: ~384 MB out, ~8 MB t in.
//
// R6 = DIAGNOSTIC bandwidth probe (R4 base + 384 MB of extra output READS).
// Two neutral rounds (NT->plain store, depth-2 t prefetch) killed both
// theories; all first-principles arithmetic says this kernel should be
// HBM-write-bound at ~62us, yet the timed graph is stuck at ~406us
// (= ~245us harness poison fill + ~130-160us kernel+overhead).
// The kernel never appears in rocprof's top-5 (all ~245us fills), so we
// have zero counter rows for it.  This round adds exactly one extra HBM
// stream: each iteration also reads out[g + total4/2] (racy garbage,
// accumulated into `sink`, stored only under the never-true guard n<0).
//   - If the kernel truly runs at ~2.4 TB/s: dur rises ~130-160us AND the
//     doubled kernel (~260-320us) enters the top-5 WITH its counters
//     (FETCH/WRITE/VALUBusy/LDS conflicts) -> real diagnosis next round.
//   - If the kernel is near the write roofline: dur rises only ~60-65us
//     and stays invisible -> residual is fixed harness overhead -> ROOFLINE.
// Correctness: the extra loads read garbage but never influence stored
// output (guard is runtime-false); every out element still gets exactly
// its correct value.

typedef float fx4 __attribute__((ext_vector_type(4)));

constexpr int NLEV = 6;
constexpr int CCH = 8;                      // channels
constexpr int ROWS_TOTAL = 504;             // 8+16+32+64+128+256
constexpr int BLK = 256;
constexpr int F4_PER_ROW = 12;              // 48 floats / 4

__global__ __launch_bounds__(BLK) void interp_multires_kernel(
    const float* __restrict__ t,
    const float* __restrict__ v0, const float* __restrict__ v1,
    const float* __restrict__ v2, const float* __restrict__ v3,
    const float* __restrict__ v4, const float* __restrict__ v5,
    float* __restrict__ out, int n)
{
    __shared__ __align__(16) float vol_lds[ROWS_TOTAL * CCH];  // 16128 B

    const int tid = threadIdx.x;

    // ---- stage all volumes into LDS once per block ----
    const float* vps[NLEV] = {v0, v1, v2, v3, v4, v5};
#pragma unroll
    for (int l = 0; l < NLEV; ++l) {
        const int sz = 8 << l;
        const int offf = (sz - 8) * CCH;
        const int n4 = sz * CCH / 4;
        fx4* dst = (fx4*)(vol_lds + offf);
        const fx4* src = (const fx4*)vps[l];
        for (int i = tid; i < n4; i += BLK) dst[i] = src[i];
    }
    __syncthreads();

    const int total4 = n * F4_PER_ROW;       // 24M, fits int32
    const int half4  = total4 >> 1;
    const int stride = gridDim.x * BLK;
    fx4* __restrict__ out4 = (fx4*)out;
    const float* outr = (const float*)out;   // read-back view (same lineage)

    float sink = 0.0f;

    for (int g = blockIdx.x * BLK + tid; g < total4; g += stride) {
        const int row = g / F4_PER_ROW;       // magic-mul div
        const int q   = g - row * F4_PER_ROW; // 0..11
        const int lvl = q >> 1;
        const int cb  = (q & 1) * 4;          // channel base 0 or 4
        const int size = 8 << lvl;

        // ---- diagnostic read stream: +384 MB HBM fetch, values unused ----
        int gr = g + half4;
        if (gr >= total4) gr -= total4;
        sink += outr[(size_t)gr * 4];         // 1 dword per 16B -> full lines fetched

        const float tc  = fminf(fmaxf(t[row], 0.0f), 1.0f);
        const float pos = tc * (float)(size - 1);
        int i0 = (int)floorf(pos);
        i0 = min(max(i0, 0), size - 2);
        const float w  = pos - (float)i0;
        const float om = 1.0f - w;

        const float* p = vol_lds + ((size - 8) + i0) * CCH + cb;
        const fx4 a = *(const fx4*)p;
        const fx4 b = *(const fx4*)(p + CCH);

        out4[g] = a * om + b * w;
    }

    if (n < 0) out[0] = sink;                 // never true: keeps loads alive
}

extern "C" void kernel_launch(void* const* d_in, const int* in_sizes, int n_in,
                              void* d_out, int out_size, void* d_ws, size_t ws_size,
                              hipStream_t stream) {
    const float* t  = (const float*)d_in[0];
    const float* v0 = (const float*)d_in[1];
    const float* v1 = (const float*)d_in[2];
    const float* v2 = (const float*)d_in[3];
    const float* v3 = (const float*)d_in[4];
    const float* v4 = (const float*)d_in[5];
    const float* v5 = (const float*)d_in[6];
    float* out = (float*)d_out;

    const int n = in_sizes[0];                    // N (t is (N,1))
    const int total4 = n * F4_PER_ROW;
    int grid = 4096;                              // persistent-ish, ~23 iters/thread
    const int max_grid = (total4 + BLK - 1) / BLK;
    if (grid > max_grid) grid = max_grid;
    interp_multires_kernel<<<grid, BLK, 0, stream>>>(t, v0, v1, v2, v3, v4, v5,
                                                     out, n);
}

// Round 4
// 400.146 us; speedup vs baseline: 1.1879x; 1.1879x over previous
//
#include <hip/hip_runtime.h>

// 1-D multi-resolution linear interp, 6 levels (sizes 8..256, 8 channels),
// N=2M points -> (N, 48) f32.  Write-bound: ~384 MB out, ~8 MB t in.
//
// R7 = revert to R3 (best harness-verified, 401.2us) after the R6
// bandwidth probe CONFIRMED the kernel is at the HBM roofline:
//   - R6 added exactly 384 MB of extra reads; dur rose only 69.4us
//     => marginal BW ~5.5 TB/s (~ achievable ceiling), and the doubled
//     kernel still did not enter rocprof's top-5.
//   - Kernel's true cost ~65-75us for 392 MB (roofline ~62us).
//   - Residual timed-graph cost is harness-fixed: ~245us poison fill of
//     1.536 GB (itself at 80% HBM peak) + ~90us of reset dispatches/gaps.
// Store flavor (NT vs plain, R4) and t-prefetch (R5) were both within
// noise; keep the best-measured variant verbatim.
//
//  - 4096 persistent-ish blocks, grid-stride over output float4 indices
//  - volumes packed once per block into LDS, single __syncthreads
//  - t direct from global (12-way reuse via L1)
//  - non-temporal dwordx4 stores (output never re-read)

typedef float fx4 __attribute__((ext_vector_type(4)));

constexpr int NLEV = 6;
constexpr int CCH = 8;                      // channels
constexpr int ROWS_TOTAL = 504;             // 8+16+32+64+128+256
constexpr int BLK = 256;
constexpr int F4_PER_ROW = 12;              // 48 floats / 4

__global__ __launch_bounds__(BLK) void interp_multires_kernel(
    const float* __restrict__ t,
    const float* __restrict__ v0, const float* __restrict__ v1,
    const float* __restrict__ v2, const float* __restrict__ v3,
    const float* __restrict__ v4, const float* __restrict__ v5,
    float* __restrict__ out, int n)
{
    __shared__ __align__(16) float vol_lds[ROWS_TOTAL * CCH];  // 16128 B

    const int tid = threadIdx.x;

    // ---- stage all volumes into LDS once per block ----
    const float* vps[NLEV] = {v0, v1, v2, v3, v4, v5};
#pragma unroll
    for (int l = 0; l < NLEV; ++l) {
        const int sz = 8 << l;
        const int offf = (sz - 8) * CCH;
        const int n4 = sz * CCH / 4;
        fx4* dst = (fx4*)(vol_lds + offf);
        const fx4* src = (const fx4*)vps[l];
        for (int i = tid; i < n4; i += BLK) dst[i] = src[i];
    }
    __syncthreads();

    const int total4 = n * F4_PER_ROW;       // 24M, fits int32
    const int stride = gridDim.x * BLK;
    fx4* __restrict__ out4 = (fx4*)out;

    for (int g = blockIdx.x * BLK + tid; g < total4; g += stride) {
        const int row = g / F4_PER_ROW;       // magic-mul div
        const int q   = g - row * F4_PER_ROW; // 0..11
        const int lvl = q >> 1;
        const int cb  = (q & 1) * 4;          // channel base 0 or 4
        const int size = 8 << lvl;

        const float tc  = fminf(fmaxf(t[row], 0.0f), 1.0f);
        const float pos = tc * (float)(size - 1);
        int i0 = (int)floorf(pos);
        i0 = min(max(i0, 0), size - 2);
        const float w  = pos - (float)i0;
        const float om = 1.0f - w;

        const float* p = vol_lds + ((size - 8) + i0) * CCH + cb;
        const fx4 a = *(const fx4*)p;
        const fx4 b = *(const fx4*)(p + CCH);

        const fx4 r = a * om + b * w;
        __builtin_nontemporal_store(r, out4 + g);
    }
}

extern "C" void kernel_launch(void* const* d_in, const int* in_sizes, int n_in,
                              void* d_out, int out_size, void* d_ws, size_t ws_size,
                              hipStream_t stream) {
    const float* t  = (const float*)d_in[0];
    const float* v0 = (const float*)d_in[1];
    const float* v1 = (const float*)d_in[2];
    const float* v2 = (const float*)d_in[3];
    const float* v3 = (const float*)d_in[4];
    const float* v4 = (const float*)d_in[5];
    const float* v5 = (const float*)d_in[6];
    float* out = (float*)d_out;

    const int n = in_sizes[0];                    // N (t is (N,1))
    const int total4 = n * F4_PER_ROW;
    int grid = 4096;                              // persistent-ish, ~23 iters/thread
    const int max_grid = (total4 + BLK - 1) / BLK;
    if (grid > max_grid) grid = max_grid;
    interp_multires_kernel<<<grid, BLK, 0, stream>>>(t, v0, v1, v2, v3, v4, v5,
                                                     out, n);
}